// Round 11
// baseline (275.738 us; speedup 1.0000x reference)
//
#include <hip/hip_runtime.h>
#include <math.h>

#define BSZ 4096
#define DIM 1024
#define NST 2900000

constexpr float GAMMA_S   = 0.8f;
constexpr float GAMMA_U   = 0.8f;
constexpr float RHO_I_C   = 0.1f;
constexpr float RHO_T_C   = 0.1f;
constexpr float C_EPS     = 1e-10f;
constexpr float TAU_MIN_C = 0.005f;
constexpr float TAU_MAX_C = 1.0f;
constexpr float GCLIP     = 5.0f;
constexpr float ETA_INIT_C = 0.01f;
constexpr float ETA_MIN_C  = 1e-4f;
constexpr float PI_F       = 3.14159265358979323846f;

typedef __bf16 bf16x8 __attribute__((ext_vector_type(8)));
typedef float  f32x4  __attribute__((ext_vector_type(4)));

__device__ __forceinline__ unsigned short f2bf(float f) {
    unsigned int u = __float_as_uint(f);
    u += 0x7fffu + ((u >> 16) & 1u);
    return (unsigned short)(u >> 16);
}
__device__ __forceinline__ float bf2f(unsigned short s) {
    return __uint_as_float(((unsigned int)s) << 16);
}

// ---------------------------------------------------------------------------
// conv_diag: fp32->bf16 features + bf16-consistent diag dot + gathers +
// zero the 3 scalar outputs. R9-proven (NT feature loads).
// ---------------------------------------------------------------------------
__global__ __launch_bounds__(256) void conv_diag(const float* __restrict__ imf,
                                                 const float* __restrict__ txf,
                                                 unsigned short* __restrict__ abf,
                                                 unsigned short* __restrict__ bbf,
                                                 const float* __restrict__ tau_I,
                                                 const float* __restrict__ tau_T,
                                                 const float* __restrict__ b_I,
                                                 const float* __restrict__ b_T,
                                                 const int* __restrict__ iid,
                                                 const int* __restrict__ tid_,
                                                 float* diag, float* tauIg, float* tauTg,
                                                 float* obI, float* obT,
                                                 float* __restrict__ scal) {
    if (blockIdx.x == 0 && threadIdx.x < 3) scal[threadIdx.x] = 0.f;
    const int w  = threadIdx.x >> 6;
    const int ln = threadIdx.x & 63;
    const int i  = blockIdx.x * 4 + w;
    float dot = 0.f;
#pragma unroll
    for (int k = 0; k < 4; ++k) {
        const int off = i * DIM + k * 256 + ln * 4;
        const f32x4 a = __builtin_nontemporal_load((const f32x4*)&imf[off]);
        const f32x4 b = __builtin_nontemporal_load((const f32x4*)&txf[off]);
        ushort4 ra, rb;
        ra.x = f2bf(a.x); ra.y = f2bf(a.y); ra.z = f2bf(a.z); ra.w = f2bf(a.w);
        rb.x = f2bf(b.x); rb.y = f2bf(b.y); rb.z = f2bf(b.z); rb.w = f2bf(b.w);
        *(ushort4*)&abf[off] = ra;
        *(ushort4*)&bbf[off] = rb;
        dot += bf2f(ra.x) * bf2f(rb.x) + bf2f(ra.y) * bf2f(rb.y) +
               bf2f(ra.z) * bf2f(rb.z) + bf2f(ra.w) * bf2f(rb.w);
    }
#pragma unroll
    for (int m = 32; m; m >>= 1) dot += __shfl_xor(dot, m);
    if (ln == 0) {
        diag[i] = dot;
        const int id = iid[i];
        tauIg[i] = tau_I[id];
        obI[i]   = b_I[id];
        const int td = tid_[i];
        tauTg[i] = tau_T[td];
        obT[i]   = b_T[td];
    }
}

// ---------------------------------------------------------------------------
// gemm_fused: R9 inner structure (274.5us session best), NEW 2:1 block mix:
// 1536 blocks in groups of 24 = 16 gemm + 8 copy (was 1:1 at 2048). Within a
// group gemm covers each XCD twice, copy once (24%8==0 keeps balance). Gemm
// is latency-bound (MfmaUtil 13%, occ 23%): raising resident gemm-wave share
// 1/2 -> 2/3 adds inter-block overlap at the two-barrier K-loop stalls.
// Copy: 512 blocks x 2x work, batch-2 NT chunks (>=5MB in flight, ample).
// Gemm gid mapping / FETCH pattern untouched (R2's confound removed).
// ---------------------------------------------------------------------------
__device__ __forceinline__ void async16(const void* g, void* l) {
    __builtin_amdgcn_global_load_lds(
        (const __attribute__((address_space(1))) void*)g,
        (__attribute__((address_space(3))) void*)l, 16, 0, 0);
}

__global__ __launch_bounds__(256) void gemm_fused(const unsigned short* __restrict__ A,
                                                  const unsigned short* __restrict__ B,
                                                  const float* __restrict__ diag,
                                                  const float* __restrict__ tauIg,
                                                  const float* __restrict__ tauTg,
                                                  float* __restrict__ rpM,
                                                  float* __restrict__ rpE,
                                                  float* __restrict__ rpV,
                                                  float* __restrict__ cpM,
                                                  float* __restrict__ cpE,
                                                  float* __restrict__ cpV,
                                                  const float* __restrict__ s_I,
                                                  const float* __restrict__ s_T,
                                                  const float* __restrict__ u_I,
                                                  const float* __restrict__ u_T,
                                                  const float* __restrict__ b_I,
                                                  const float* __restrict__ b_T,
                                                  const float* __restrict__ tau_I,
                                                  const float* __restrict__ tau_T,
                                                  float* __restrict__ outbase) {
    __shared__ unsigned short As[128 * 32];   // 8 KB
    __shared__ unsigned short Bs[128 * 32];   // 8 KB

    const int tid = threadIdx.x;
    const int grp = blockIdx.x / 24;          // 0..63
    const int off = blockIdx.x % 24;          // 0..23 (XCD = blockIdx%8; 24%8==0)

    if (off >= 16) {
        // ------------- copy path (512 blocks, 2x work, NT batch-2) -------------
        const size_t idx = (size_t)(grp * 8 + (off - 16)) * 256 + tid;
        const size_t stride = (size_t)512 * 256;
        const size_t NV = (NST - 1) / 4;
        const float* srcs[8] = {s_I, s_T, u_I, u_T, b_I, b_T, tau_I, tau_T};
#pragma unroll
        for (int a = 0; a < 8; ++a) {
            const float* s = srcs[a];
            float* d = outbase + (size_t)a * NST;
            size_t c = idx;
            for (; c + stride < NV; c += 2 * stride) {
                const size_t c2 = c + stride;
                const f32x4 f0 = __builtin_nontemporal_load((const f32x4*)&s[4 * c]);
                const f32x4 f1 = __builtin_nontemporal_load((const f32x4*)&s[4 * c2]);
                const float nx0 = __builtin_nontemporal_load(&s[4 * c + 4]);
                const float nx1 = __builtin_nontemporal_load(&s[4 * c2 + 4]);
                f32x4 v0; v0.x = f0.y; v0.y = f0.z; v0.z = f0.w; v0.w = nx0;
                f32x4 v1; v1.x = f1.y; v1.y = f1.z; v1.z = f1.w; v1.w = nx1;
                __builtin_nontemporal_store(v0, (f32x4*)&d[1 + 4 * c]);
                __builtin_nontemporal_store(v1, (f32x4*)&d[1 + 4 * c2]);
            }
            if (c < NV) {
                const f32x4 f = __builtin_nontemporal_load((const f32x4*)&s[4 * c]);
                const float nx = __builtin_nontemporal_load(&s[4 * c + 4]);
                f32x4 v; v.x = f.y; v.y = f.z; v.z = f.w; v.w = nx;
                __builtin_nontemporal_store(v, (f32x4*)&d[1 + 4 * c]);
            }
            if (idx == 0) d[0] = s[0];
            if (idx < 3)  d[NST - 3 + idx] = s[NST - 3 + idx];
        }
        return;
    }

    // ---------------- gemm path ----------------
    const int gid = grp * 16 + off;           // 0..1023, same mapping as R9
    const int bjIdx = gid & 31, biIdx = gid >> 5;
    const int bi = biIdx * 128;
    const int bj = bjIdx * 128;
    const int lane = tid & 63;
    const int wave = tid >> 6;
    const int m_base = (wave >> 1) * 64;
    const int n_base = (wave & 1) * 64;

    // staging: chunk c -> LDS row c>>2, slot c&3; global k-chunk = slot ^ ((row>>1)&3)
    const int c0 = tid, c1 = tid + 256;
    const int r0 = c0 >> 2, kg0 = ((c0 & 3) ^ ((r0 >> 1) & 3)) * 8;
    const int r1 = c1 >> 2, kg1 = ((c1 & 3) ^ ((r1 >> 1) & 3)) * 8;

    f32x4 acc[4][4];
#pragma unroll
    for (int m = 0; m < 4; ++m)
#pragma unroll
        for (int n = 0; n < 4; ++n)
            acc[m][n] = (f32x4){0.f, 0.f, 0.f, 0.f};

    const int mrow = lane & 15;
    const int q    = lane >> 4;

    for (int k0 = 0; k0 < DIM; k0 += 32) {
        __syncthreads();
        async16(&A[(size_t)(bi + r0) * DIM + k0 + kg0], &As[c0 * 8]);
        async16(&A[(size_t)(bi + r1) * DIM + k0 + kg1], &As[c1 * 8]);
        async16(&B[(size_t)(bj + r0) * DIM + k0 + kg0], &Bs[c0 * 8]);
        async16(&B[(size_t)(bj + r1) * DIM + k0 + kg1], &Bs[c1 * 8]);
        __syncthreads();

        __builtin_amdgcn_s_setprio(1);
        bf16x8 af[4], bfr[4];
#pragma unroll
        for (int t = 0; t < 4; ++t) {
            const int rlA = m_base + t * 16 + mrow;
            const int rlB = n_base + t * 16 + mrow;
            af[t]  = *(const bf16x8*)&As[rlA * 32 + (q ^ ((rlA >> 1) & 3)) * 8];
            bfr[t] = *(const bf16x8*)&Bs[rlB * 32 + (q ^ ((rlB >> 1) & 3)) * 8];
        }
#pragma unroll
        for (int mt = 0; mt < 4; ++mt)
#pragma unroll
            for (int nt = 0; nt < 4; ++nt)
                acc[mt][nt] = __builtin_amdgcn_mfma_f32_16x16x32_bf16(
                    af[mt], bfr[nt], acc[mt][nt], 0, 0, 0);
        __builtin_amdgcn_s_setprio(0);
    }

    // ---- online-softmax epilogue (unchanged, proven) ----
    __syncthreads();
    float* prm = (float*)Bs;   // [0..127]=diag row, [128..255]=itau row,
                               // [256..383]=diag col, [384..511]=itau col
    if (tid < 128) {
        prm[tid]       = diag[bi + tid];
        prm[128 + tid] = 1.0f / tauIg[bi + tid];
        prm[256 + tid] = diag[bj + tid];
        prm[384 + tid] = 1.0f / tauTg[bj + tid];
    }
    __syncthreads();

    float* red = (float*)As;   // rowM 0..255, rowE 256..511, rowV 512..767,
                               // colM 768..1023, colE 1024..1279, colV 1280..1535
    const int rowq = (lane >> 4) * 4;

    // image (row) side
#pragma unroll
    for (int mt = 0; mt < 4; ++mt)
#pragma unroll
        for (int r = 0; r < 4; ++r) {
            const int row_l = m_base + mt * 16 + rowq + r;
            const float dgr = prm[row_l];
            const float itr = prm[128 + row_l];
            float v0 = (acc[mt][0][r] - dgr) * itr;
            float v1 = (acc[mt][1][r] - dgr) * itr;
            float v2 = (acc[mt][2][r] - dgr) * itr;
            float v3 = (acc[mt][3][r] - dgr) * itr;
            float m = fmaxf(fmaxf(v0, v1), fmaxf(v2, v3));
#pragma unroll
            for (int x = 1; x <= 8; x <<= 1) m = fmaxf(m, __shfl_xor(m, x));
            const float e0 = __expf(v0 - m), e1 = __expf(v1 - m);
            const float e2 = __expf(v2 - m), e3 = __expf(v3 - m);
            float se = e0 + e1 + e2 + e3;
            float sv = e0 * v0 + e1 * v1 + e2 * v2 + e3 * v3;
#pragma unroll
            for (int x = 1; x <= 8; x <<= 1) {
                se += __shfl_xor(se, x);
                sv += __shfl_xor(sv, x);
            }
            if ((lane & 15) == 0) {
                const int idx = wave * 64 + mt * 16 + rowq + r;
                red[idx] = m; red[256 + idx] = se; red[512 + idx] = sv;
            }
        }

    // text (col) side
#pragma unroll
    for (int nt = 0; nt < 4; ++nt) {
        const int col_l = n_base + nt * 16 + (lane & 15);
        const float dgc = prm[256 + col_l];
        const float itc = prm[384 + col_l];
        float m = -INFINITY;
#pragma unroll
        for (int mt = 0; mt < 4; ++mt)
#pragma unroll
            for (int r = 0; r < 4; ++r)
                m = fmaxf(m, (acc[mt][nt][r] - dgc) * itc);
        m = fmaxf(m, __shfl_xor(m, 16));
        m = fmaxf(m, __shfl_xor(m, 32));
        float se = 0.f, sv = 0.f;
#pragma unroll
        for (int mt = 0; mt < 4; ++mt)
#pragma unroll
            for (int r = 0; r < 4; ++r) {
                const float v = (acc[mt][nt][r] - dgc) * itc;
                const float e = __expf(v - m);
                se += e; sv += e * v;
            }
        se += __shfl_xor(se, 16); se += __shfl_xor(se, 32);
        sv += __shfl_xor(sv, 16); sv += __shfl_xor(sv, 32);
        if (lane < 16) {
            const int idx = wave * 64 + nt * 16 + lane;
            red[768 + idx] = m; red[1024 + idx] = se; red[1280 + idx] = sv;
        }
    }
    __syncthreads();

    if (tid < 128) {
        const int rg = tid, li = rg & 63;
        const int w0 = (rg >> 6) * 2, w1 = w0 + 1;
        const float mA = red[w0 * 64 + li], mB = red[w1 * 64 + li];
        const float M = fmaxf(mA, mB);
        const float fA = __expf(mA - M), fB = __expf(mB - M);
        const size_t o = (size_t)bjIdx * BSZ + bi + rg;
        rpM[o] = M;
        rpE[o] = red[256 + w0 * 64 + li] * fA + red[256 + w1 * 64 + li] * fB;
        rpV[o] = red[512 + w0 * 64 + li] * fA + red[512 + w1 * 64 + li] * fB;
    } else {
        const int cg = tid - 128, li = cg & 63;
        const int w0 = cg >> 6, w1 = w0 + 2;
        const float mA = red[768 + w0 * 64 + li], mB = red[768 + w1 * 64 + li];
        const float M = fmaxf(mA, mB);
        const float fA = __expf(mA - M), fB = __expf(mB - M);
        const size_t o = (size_t)biIdx * BSZ + bj + cg;
        cpM[o] = M;
        cpE[o] = red[1024 + w0 * 64 + li] * fA + red[1024 + w1 * 64 + li] * fB;
        cpV[o] = red[1280 + w0 * 64 + li] * fA + red[1280 + w1 * 64 + li] * fB;
    }
}

// ---------------------------------------------------------------------------
// Finalize: R4-proven 128-block version, unchanged. Runs last (kernel
// boundary ordering): overwrites the copied state at the gathered ids.
// ---------------------------------------------------------------------------
__global__ __launch_bounds__(256) void finalize(const float* __restrict__ s_I,
                                                const float* __restrict__ s_T,
                                                const float* __restrict__ u_I,
                                                const float* __restrict__ u_T,
                                                const int* __restrict__ iid,
                                                const int* __restrict__ tid_,
                                                const int* __restrict__ epoch,
                                                const int* __restrict__ maxep,
                                                const float* __restrict__ tauIg,
                                                const float* __restrict__ tauTg,
                                                const float* __restrict__ obI,
                                                const float* __restrict__ obT,
                                                const float* __restrict__ rpM,
                                                const float* __restrict__ rpE,
                                                const float* __restrict__ rpV,
                                                const float* __restrict__ cpM,
                                                const float* __restrict__ cpE,
                                                const float* __restrict__ cpV,
                                                float* __restrict__ out) {
    const int side = blockIdx.x & 1;                  // 0 = image, 1 = text
    const int i0   = (blockIdx.x >> 1) * 64;
    const int w    = threadIdx.x >> 6;
    const int il   = threadIdx.x & 63;
    const int i    = i0 + il;

    const float* pM  = side ? cpM  : rpM;
    const float* pE  = side ? cpE  : rpE;
    const float* pV  = side ? cpV  : rpV;
    const float* tg  = side ? tauTg : tauIg;
    const float* obA = side ? obT  : obI;
    const float* sA  = side ? s_T  : s_I;
    const float* uA  = side ? u_T  : u_I;
    const int*   ids = side ? tid_ : iid;
    const float  rho = side ? RHO_T_C : RHO_I_C;

    float M[8], E[8], V[8];
#pragma unroll
    for (int k = 0; k < 8; ++k) {
        const size_t o = (size_t)(w * 8 + k) * BSZ + i;
        M[k] = pM[o]; E[k] = pE[o]; V[k] = pV[o];
    }
    float pm = M[0];
#pragma unroll
    for (int k = 1; k < 8; ++k) pm = fmaxf(pm, M[k]);

    __shared__ float lred[12][64];   // [0..3]=pmax, [4..7]=se, [8..11]=sv
    lred[w][il] = pm;
    __syncthreads();

    const float ob = obA[i];
    const float nb = fmaxf(fmaxf(fmaxf(lred[0][il], lred[1][il]),
                                 fmaxf(lred[2][il], lred[3][il])), ob);
    float se = 0.f, sv = 0.f;
#pragma unroll
    for (int k = 0; k < 8; ++k) {
        const float f = __expf(M[k] - nb);
        se += E[k] * f;
        sv += V[k] * f;
    }
    lred[4 + w][il] = se;
    lred[8 + w][il] = sv;
    __syncthreads();

    if (w == 0) {
        const float eta = ETA_MIN_C + (ETA_INIT_C - ETA_MIN_C) *
                          cosf(0.5f * PI_F * ((float)epoch[0] / (float)maxep[0]));
        const float invBm1 = 1.0f / (float)(BSZ - 1);
        const float invB   = 1.0f / (float)BSZ;

        const int   id  = ids[i];
        const float tau = tg[i];
        const float seT = (lred[4][il] + lred[5][il]) + (lred[6][il] + lred[7][il]);
        const float svT = (lred[8][il] + lred[9][il]) + (lred[10][il] + lred[11][il]);

        const float g     = seT * invBm1;
        const float s_new = (1.f - GAMMA_S) * sA[id] * __expf(ob - nb) + GAMMA_S * g;
        const float W     = svT * invBm1 / (s_new + C_EPS);
        const float grad  = logf(s_new) + nb + rho - W;
        const float gc    = fminf(fmaxf(grad, -GCLIP), GCLIP);
        const float u_new = (1.f - GAMMA_U) * uA[id] + GAMMA_U * gc;
        const float tau_new = fminf(fmaxf(tau - eta * u_new, TAU_MIN_C), TAU_MAX_C);

        float* stb   = out + 4 * BSZ + 3;
        float* o_g   = out + side * BSZ;           // g_I / g_T
        float* o_gt  = out + (2 + side) * BSZ;     // grad_tau_image / _text
        float* o_s   = stb + (size_t)side * NST;
        float* o_u   = stb + (size_t)(2 + side) * NST;
        float* o_b   = stb + (size_t)(4 + side) * NST;
        float* o_t   = stb + (size_t)(6 + side) * NST;

        o_g[i]  = g;
        o_gt[i] = grad;
        o_s[id] = s_new;
        o_u[id] = u_new;
        o_b[id] = nb;
        o_t[id] = tau_new;

        float v0 = tau * W * invB;   // loss contribution
        float v1 = tau * invB;       // avg-tau contribution
#pragma unroll
        for (int o2 = 32; o2; o2 >>= 1) {
            v0 += __shfl_down(v0, o2);
            v1 += __shfl_down(v1, o2);
        }
        if (il == 0) {
            atomicAdd(&out[4 * BSZ + 0], v0);
            atomicAdd(&out[4 * BSZ + 1 + side], v1);
        }
    }
}

// ---------------------------------------------------------------------------
extern "C" void kernel_launch(void* const* d_in, const int* in_sizes, int n_in,
                              void* d_out, int out_size, void* d_ws, size_t ws_size,
                              hipStream_t stream) {
    const float* imf   = (const float*)d_in[0];
    const float* txf   = (const float*)d_in[1];
    const float* s_I   = (const float*)d_in[2];
    const float* s_T   = (const float*)d_in[3];
    const float* tau_I = (const float*)d_in[4];
    const float* tau_T = (const float*)d_in[5];
    const float* u_I   = (const float*)d_in[6];
    const float* u_T   = (const float*)d_in[7];
    const float* b_I   = (const float*)d_in[8];
    const float* b_T   = (const float*)d_in[9];
    const int* iid     = (const int*)d_in[10];
    const int* tid_    = (const int*)d_in[11];
    const int* epoch   = (const int*)d_in[12];
    const int* maxep   = (const int*)d_in[13];

    float* out = (float*)d_out;
    float* ws  = (float*)d_ws;

    float* diag  = ws + 0 * BSZ;
    float* tauIg = ws + 1 * BSZ;
    float* tauTg = ws + 2 * BSZ;
    float* obI   = ws + 3 * BSZ;
    float* obT   = ws + 4 * BSZ;
    float* rpM   = ws + 5 * BSZ;                   // 32 * BSZ each
    float* rpE   = rpM + (size_t)32 * BSZ;
    float* rpV   = rpE + (size_t)32 * BSZ;
    float* cpM   = rpV + (size_t)32 * BSZ;
    float* cpE   = cpM + (size_t)32 * BSZ;
    float* cpV   = cpE + (size_t)32 * BSZ;
    unsigned short* abf = (unsigned short*)(cpV + (size_t)32 * BSZ);
    unsigned short* bbf = abf + (size_t)BSZ * DIM;

    conv_diag<<<BSZ / 4, 256, 0, stream>>>(imf, txf, abf, bbf, tau_I, tau_T, b_I, b_T,
                                           iid, tid_, diag, tauIg, tauTg, obI, obT,
                                           out + 4 * BSZ);
    gemm_fused<<<1536, 256, 0, stream>>>(abf, bbf, diag, tauIg, tauTg,
                                         rpM, rpE, rpV, cpM, cpE, cpV,
                                         s_I, s_T, u_I, u_T, b_I, b_T, tau_I, tau_T,
                                         out + 4 * BSZ + 3);
    finalize<<<128, 256, 0, stream>>>(s_I, s_T, u_I, u_T, iid, tid_, epoch, maxep,
                                      tauIg, tauTg, obI, obT,
                                      rpM, rpE, rpV, cpM, cpE, cpV, out);
}

// Round 12
// 272.942 us; speedup vs baseline: 1.0102x; 1.0102x over previous
//
#include <hip/hip_runtime.h>
#include <math.h>

#define BSZ 4096
#define DIM 1024
#define NST 2900000

constexpr float GAMMA_S   = 0.8f;
constexpr float GAMMA_U   = 0.8f;
constexpr float RHO_I_C   = 0.1f;
constexpr float RHO_T_C   = 0.1f;
constexpr float C_EPS     = 1e-10f;
constexpr float TAU_MIN_C = 0.005f;
constexpr float TAU_MAX_C = 1.0f;
constexpr float GCLIP     = 5.0f;
constexpr float ETA_INIT_C = 0.01f;
constexpr float ETA_MIN_C  = 1e-4f;
constexpr float PI_F       = 3.14159265358979323846f;

typedef __bf16 bf16x8 __attribute__((ext_vector_type(8)));
typedef float  f32x4  __attribute__((ext_vector_type(4)));

__device__ __forceinline__ unsigned short f2bf(float f) {
    unsigned int u = __float_as_uint(f);
    u += 0x7fffu + ((u >> 16) & 1u);
    return (unsigned short)(u >> 16);
}
__device__ __forceinline__ float bf2f(unsigned short s) {
    return __uint_as_float(((unsigned int)s) << 16);
}

// ---------------------------------------------------------------------------
// conv_diag: fp32->bf16 features + bf16-consistent diag dot + gathers +
// zero the 3 scalar outputs. NT feature loads (touch-once 32MB stream; keep
// L3 lines free for gemm's A/B panels). Session-best (R9) version.
// ---------------------------------------------------------------------------
__global__ __launch_bounds__(256) void conv_diag(const float* __restrict__ imf,
                                                 const float* __restrict__ txf,
                                                 unsigned short* __restrict__ abf,
                                                 unsigned short* __restrict__ bbf,
                                                 const float* __restrict__ tau_I,
                                                 const float* __restrict__ tau_T,
                                                 const float* __restrict__ b_I,
                                                 const float* __restrict__ b_T,
                                                 const int* __restrict__ iid,
                                                 const int* __restrict__ tid_,
                                                 float* diag, float* tauIg, float* tauTg,
                                                 float* obI, float* obT,
                                                 float* __restrict__ scal) {
    if (blockIdx.x == 0 && threadIdx.x < 3) scal[threadIdx.x] = 0.f;
    const int w  = threadIdx.x >> 6;
    const int ln = threadIdx.x & 63;
    const int i  = blockIdx.x * 4 + w;
    float dot = 0.f;
#pragma unroll
    for (int k = 0; k < 4; ++k) {
        const int off = i * DIM + k * 256 + ln * 4;
        const f32x4 a = __builtin_nontemporal_load((const f32x4*)&imf[off]);
        const f32x4 b = __builtin_nontemporal_load((const f32x4*)&txf[off]);
        ushort4 ra, rb;
        ra.x = f2bf(a.x); ra.y = f2bf(a.y); ra.z = f2bf(a.z); ra.w = f2bf(a.w);
        rb.x = f2bf(b.x); rb.y = f2bf(b.y); rb.z = f2bf(b.z); rb.w = f2bf(b.w);
        *(ushort4*)&abf[off] = ra;
        *(ushort4*)&bbf[off] = rb;
        dot += bf2f(ra.x) * bf2f(rb.x) + bf2f(ra.y) * bf2f(rb.y) +
               bf2f(ra.z) * bf2f(rb.z) + bf2f(ra.w) * bf2f(rb.w);
    }
#pragma unroll
    for (int m = 32; m; m >>= 1) dot += __shfl_xor(dot, m);
    if (ln == 0) {
        diag[i] = dot;
        const int id = iid[i];
        tauIg[i] = tau_I[id];
        obI[i]   = b_I[id];
        const int td = tid_[i];
        tauTg[i] = tau_T[td];
        obT[i]   = b_T[td];
    }
}

// ---------------------------------------------------------------------------
// gemm_fused: session-best (R9, 274.5us) configuration. 128x128 tile, BK=32,
// 16KB LDS single-buffer, even/odd XCD-balanced 1:1 gemm/copy block split,
// setprio(1) over ds_read+MFMA (T5: role-diverse waves on each CU), copy as
// NT aligned-src batch-2 stream. Verified micro-delta history:
//   setprio+NT: 115->105.5us; aligned src 5->3 VMEM/chunk: ->102.3us.
// Structural rewrites (BK=64, dbuf+syncthreads, XCD chunking, serial split,
// copy-first, 2:1 mix) all regressed or neutral — 2-barrier K-loop retained.
// ---------------------------------------------------------------------------
__device__ __forceinline__ void async16(const void* g, void* l) {
    __builtin_amdgcn_global_load_lds(
        (const __attribute__((address_space(1))) void*)g,
        (__attribute__((address_space(3))) void*)l, 16, 0, 0);
}

__global__ __launch_bounds__(256) void gemm_fused(const unsigned short* __restrict__ A,
                                                  const unsigned short* __restrict__ B,
                                                  const float* __restrict__ diag,
                                                  const float* __restrict__ tauIg,
                                                  const float* __restrict__ tauTg,
                                                  float* __restrict__ rpM,
                                                  float* __restrict__ rpE,
                                                  float* __restrict__ rpV,
                                                  float* __restrict__ cpM,
                                                  float* __restrict__ cpE,
                                                  float* __restrict__ cpV,
                                                  const float* __restrict__ s_I,
                                                  const float* __restrict__ s_T,
                                                  const float* __restrict__ u_I,
                                                  const float* __restrict__ u_T,
                                                  const float* __restrict__ b_I,
                                                  const float* __restrict__ b_T,
                                                  const float* __restrict__ tau_I,
                                                  const float* __restrict__ tau_T,
                                                  float* __restrict__ outbase) {
    __shared__ unsigned short As[128 * 32];   // 8 KB
    __shared__ unsigned short Bs[128 * 32];   // 8 KB

    const int tid = threadIdx.x;
    const int gid = ((blockIdx.x >> 4) << 3) | (blockIdx.x & 7);   // 0..1023

    if ((blockIdx.x >> 3) & 1) {
        // ------------- copy path (nontemporal, aligned src, batch-2) -------------
        const size_t idx = (size_t)gid * 256 + tid;
        const size_t stride = (size_t)1024 * 256;
        const size_t NV = (NST - 1) / 4;
        const float* srcs[8] = {s_I, s_T, u_I, u_T, b_I, b_T, tau_I, tau_T};
#pragma unroll
        for (int a = 0; a < 8; ++a) {
            const float* s = srcs[a];
            float* d = outbase + (size_t)a * NST;
            size_t c = idx;
            // pair loop: 2 loads in flight before either store
            for (; c + stride < NV; c += 2 * stride) {
                const size_t c2 = c + stride;
                const f32x4 f0 = __builtin_nontemporal_load((const f32x4*)&s[4 * c]);
                const f32x4 f1 = __builtin_nontemporal_load((const f32x4*)&s[4 * c2]);
                const float nx0 = __builtin_nontemporal_load(&s[4 * c + 4]);
                const float nx1 = __builtin_nontemporal_load(&s[4 * c2 + 4]);
                f32x4 v0; v0.x = f0.y; v0.y = f0.z; v0.z = f0.w; v0.w = nx0;
                f32x4 v1; v1.x = f1.y; v1.y = f1.z; v1.z = f1.w; v1.w = nx1;
                __builtin_nontemporal_store(v0, (f32x4*)&d[1 + 4 * c]);
                __builtin_nontemporal_store(v1, (f32x4*)&d[1 + 4 * c2]);
            }
            if (c < NV) {   // leftover single chunk
                const f32x4 f = __builtin_nontemporal_load((const f32x4*)&s[4 * c]);
                const float nx = __builtin_nontemporal_load(&s[4 * c + 4]);
                f32x4 v; v.x = f.y; v.y = f.z; v.z = f.w; v.w = nx;
                __builtin_nontemporal_store(v, (f32x4*)&d[1 + 4 * c]);
            }
            if (idx == 0) d[0] = s[0];
            if (idx < 3)  d[NST - 3 + idx] = s[NST - 3 + idx];
        }
        return;
    }

    // ---------------- gemm path ----------------
    const int bjIdx = gid & 31, biIdx = gid >> 5;
    const int bi = biIdx * 128;
    const int bj = bjIdx * 128;
    const int lane = tid & 63;
    const int wave = tid >> 6;
    const int m_base = (wave >> 1) * 64;
    const int n_base = (wave & 1) * 64;

    // staging: chunk c -> LDS row c>>2, slot c&3; global k-chunk = slot ^ ((row>>1)&3)
    const int c0 = tid, c1 = tid + 256;
    const int r0 = c0 >> 2, kg0 = ((c0 & 3) ^ ((r0 >> 1) & 3)) * 8;
    const int r1 = c1 >> 2, kg1 = ((c1 & 3) ^ ((r1 >> 1) & 3)) * 8;

    f32x4 acc[4][4];
#pragma unroll
    for (int m = 0; m < 4; ++m)
#pragma unroll
        for (int n = 0; n < 4; ++n)
            acc[m][n] = (f32x4){0.f, 0.f, 0.f, 0.f};

    const int mrow = lane & 15;
    const int q    = lane >> 4;

    for (int k0 = 0; k0 < DIM; k0 += 32) {
        __syncthreads();
        async16(&A[(size_t)(bi + r0) * DIM + k0 + kg0], &As[c0 * 8]);
        async16(&A[(size_t)(bi + r1) * DIM + k0 + kg1], &As[c1 * 8]);
        async16(&B[(size_t)(bj + r0) * DIM + k0 + kg0], &Bs[c0 * 8]);
        async16(&B[(size_t)(bj + r1) * DIM + k0 + kg1], &Bs[c1 * 8]);
        __syncthreads();

        __builtin_amdgcn_s_setprio(1);
        bf16x8 af[4], bfr[4];
#pragma unroll
        for (int t = 0; t < 4; ++t) {
            const int rlA = m_base + t * 16 + mrow;
            const int rlB = n_base + t * 16 + mrow;
            af[t]  = *(const bf16x8*)&As[rlA * 32 + (q ^ ((rlA >> 1) & 3)) * 8];
            bfr[t] = *(const bf16x8*)&Bs[rlB * 32 + (q ^ ((rlB >> 1) & 3)) * 8];
        }
#pragma unroll
        for (int mt = 0; mt < 4; ++mt)
#pragma unroll
            for (int nt = 0; nt < 4; ++nt)
                acc[mt][nt] = __builtin_amdgcn_mfma_f32_16x16x32_bf16(
                    af[mt], bfr[nt], acc[mt][nt], 0, 0, 0);
        __builtin_amdgcn_s_setprio(0);
    }

    // ---- online-softmax epilogue (proven) ----
    __syncthreads();
    float* prm = (float*)Bs;   // [0..127]=diag row, [128..255]=itau row,
                               // [256..383]=diag col, [384..511]=itau col
    if (tid < 128) {
        prm[tid]       = diag[bi + tid];
        prm[128 + tid] = 1.0f / tauIg[bi + tid];
        prm[256 + tid] = diag[bj + tid];
        prm[384 + tid] = 1.0f / tauTg[bj + tid];
    }
    __syncthreads();

    float* red = (float*)As;   // rowM 0..255, rowE 256..511, rowV 512..767,
                               // colM 768..1023, colE 1024..1279, colV 1280..1535
    const int rowq = (lane >> 4) * 4;

    // image (row) side
#pragma unroll
    for (int mt = 0; mt < 4; ++mt)
#pragma unroll
        for (int r = 0; r < 4; ++r) {
            const int row_l = m_base + mt * 16 + rowq + r;
            const float dgr = prm[row_l];
            const float itr = prm[128 + row_l];
            float v0 = (acc[mt][0][r] - dgr) * itr;
            float v1 = (acc[mt][1][r] - dgr) * itr;
            float v2 = (acc[mt][2][r] - dgr) * itr;
            float v3 = (acc[mt][3][r] - dgr) * itr;
            float m = fmaxf(fmaxf(v0, v1), fmaxf(v2, v3));
#pragma unroll
            for (int x = 1; x <= 8; x <<= 1) m = fmaxf(m, __shfl_xor(m, x));
            const float e0 = __expf(v0 - m), e1 = __expf(v1 - m);
            const float e2 = __expf(v2 - m), e3 = __expf(v3 - m);
            float se = e0 + e1 + e2 + e3;
            float sv = e0 * v0 + e1 * v1 + e2 * v2 + e3 * v3;
#pragma unroll
            for (int x = 1; x <= 8; x <<= 1) {
                se += __shfl_xor(se, x);
                sv += __shfl_xor(sv, x);
            }
            if ((lane & 15) == 0) {
                const int idx = wave * 64 + mt * 16 + rowq + r;
                red[idx] = m; red[256 + idx] = se; red[512 + idx] = sv;
            }
        }

    // text (col) side
#pragma unroll
    for (int nt = 0; nt < 4; ++nt) {
        const int col_l = n_base + nt * 16 + (lane & 15);
        const float dgc = prm[256 + col_l];
        const float itc = prm[384 + col_l];
        float m = -INFINITY;
#pragma unroll
        for (int mt = 0; mt < 4; ++mt)
#pragma unroll
            for (int r = 0; r < 4; ++r)
                m = fmaxf(m, (acc[mt][nt][r] - dgc) * itc);
        m = fmaxf(m, __shfl_xor(m, 16));
        m = fmaxf(m, __shfl_xor(m, 32));
        float se = 0.f, sv = 0.f;
#pragma unroll
        for (int mt = 0; mt < 4; ++mt)
#pragma unroll
            for (int r = 0; r < 4; ++r) {
                const float v = (acc[mt][nt][r] - dgc) * itc;
                const float e = __expf(v - m);
                se += e; sv += e * v;
            }
        se += __shfl_xor(se, 16); se += __shfl_xor(se, 32);
        sv += __shfl_xor(sv, 16); sv += __shfl_xor(sv, 32);
        if (lane < 16) {
            const int idx = wave * 64 + nt * 16 + lane;
            red[768 + idx] = m; red[1024 + idx] = se; red[1280 + idx] = sv;
        }
    }
    __syncthreads();

    if (tid < 128) {
        const int rg = tid, li = rg & 63;
        const int w0 = (rg >> 6) * 2, w1 = w0 + 1;
        const float mA = red[w0 * 64 + li], mB = red[w1 * 64 + li];
        const float M = fmaxf(mA, mB);
        const float fA = __expf(mA - M), fB = __expf(mB - M);
        const size_t o = (size_t)bjIdx * BSZ + bi + rg;
        rpM[o] = M;
        rpE[o] = red[256 + w0 * 64 + li] * fA + red[256 + w1 * 64 + li] * fB;
        rpV[o] = red[512 + w0 * 64 + li] * fA + red[512 + w1 * 64 + li] * fB;
    } else {
        const int cg = tid - 128, li = cg & 63;
        const int w0 = cg >> 6, w1 = w0 + 2;
        const float mA = red[768 + w0 * 64 + li], mB = red[768 + w1 * 64 + li];
        const float M = fmaxf(mA, mB);
        const float fA = __expf(mA - M), fB = __expf(mB - M);
        const size_t o = (size_t)biIdx * BSZ + bj + cg;
        cpM[o] = M;
        cpE[o] = red[1024 + w0 * 64 + li] * fA + red[1024 + w1 * 64 + li] * fB;
        cpV[o] = red[1280 + w0 * 64 + li] * fA + red[1280 + w1 * 64 + li] * fB;
    }
}

// ---------------------------------------------------------------------------
// Finalize: 128 blocks (side x 64-row group). Wave w reduces partial chunks
// [8w, 8w+8); LDS combine across waves; wave 0 does the scalar tail.
// Runs last (kernel boundary ordering): overwrites copied state at ids.
// ---------------------------------------------------------------------------
__global__ __launch_bounds__(256) void finalize(const float* __restrict__ s_I,
                                                const float* __restrict__ s_T,
                                                const float* __restrict__ u_I,
                                                const float* __restrict__ u_T,
                                                const int* __restrict__ iid,
                                                const int* __restrict__ tid_,
                                                const int* __restrict__ epoch,
                                                const int* __restrict__ maxep,
                                                const float* __restrict__ tauIg,
                                                const float* __restrict__ tauTg,
                                                const float* __restrict__ obI,
                                                const float* __restrict__ obT,
                                                const float* __restrict__ rpM,
                                                const float* __restrict__ rpE,
                                                const float* __restrict__ rpV,
                                                const float* __restrict__ cpM,
                                                const float* __restrict__ cpE,
                                                const float* __restrict__ cpV,
                                                float* __restrict__ out) {
    const int side = blockIdx.x & 1;                  // 0 = image, 1 = text
    const int i0   = (blockIdx.x >> 1) * 64;
    const int w    = threadIdx.x >> 6;
    const int il   = threadIdx.x & 63;
    const int i    = i0 + il;

    const float* pM  = side ? cpM  : rpM;
    const float* pE  = side ? cpE  : rpE;
    const float* pV  = side ? cpV  : rpV;
    const float* tg  = side ? tauTg : tauIg;
    const float* obA = side ? obT  : obI;
    const float* sA  = side ? s_T  : s_I;
    const float* uA  = side ? u_T  : u_I;
    const int*   ids = side ? tid_ : iid;
    const float  rho = side ? RHO_T_C : RHO_I_C;

    float M[8], E[8], V[8];
#pragma unroll
    for (int k = 0; k < 8; ++k) {
        const size_t o = (size_t)(w * 8 + k) * BSZ + i;
        M[k] = pM[o]; E[k] = pE[o]; V[k] = pV[o];
    }
    float pm = M[0];
#pragma unroll
    for (int k = 1; k < 8; ++k) pm = fmaxf(pm, M[k]);

    __shared__ float lred[12][64];   // [0..3]=pmax, [4..7]=se, [8..11]=sv
    lred[w][il] = pm;
    __syncthreads();

    const float ob = obA[i];
    const float nb = fmaxf(fmaxf(fmaxf(lred[0][il], lred[1][il]),
                                 fmaxf(lred[2][il], lred[3][il])), ob);
    float se = 0.f, sv = 0.f;
#pragma unroll
    for (int k = 0; k < 8; ++k) {
        const float f = __expf(M[k] - nb);
        se += E[k] * f;
        sv += V[k] * f;
    }
    lred[4 + w][il] = se;
    lred[8 + w][il] = sv;
    __syncthreads();

    if (w == 0) {
        const float eta = ETA_MIN_C + (ETA_INIT_C - ETA_MIN_C) *
                          cosf(0.5f * PI_F * ((float)epoch[0] / (float)maxep[0]));
        const float invBm1 = 1.0f / (float)(BSZ - 1);
        const float invB   = 1.0f / (float)BSZ;

        const int   id  = ids[i];
        const float tau = tg[i];
        const float seT = (lred[4][il] + lred[5][il]) + (lred[6][il] + lred[7][il]);
        const float svT = (lred[8][il] + lred[9][il]) + (lred[10][il] + lred[11][il]);

        const float g     = seT * invBm1;
        const float s_new = (1.f - GAMMA_S) * sA[id] * __expf(ob - nb) + GAMMA_S * g;
        const float W     = svT * invBm1 / (s_new + C_EPS);
        const float grad  = logf(s_new) + nb + rho - W;
        const float gc    = fminf(fmaxf(grad, -GCLIP), GCLIP);
        const float u_new = (1.f - GAMMA_U) * uA[id] + GAMMA_U * gc;
        const float tau_new = fminf(fmaxf(tau - eta * u_new, TAU_MIN_C), TAU_MAX_C);

        float* stb   = out + 4 * BSZ + 3;
        float* o_g   = out + side * BSZ;           // g_I / g_T
        float* o_gt  = out + (2 + side) * BSZ;     // grad_tau_image / _text
        float* o_s   = stb + (size_t)side * NST;
        float* o_u   = stb + (size_t)(2 + side) * NST;
        float* o_b   = stb + (size_t)(4 + side) * NST;
        float* o_t   = stb + (size_t)(6 + side) * NST;

        o_g[i]  = g;
        o_gt[i] = grad;
        o_s[id] = s_new;
        o_u[id] = u_new;
        o_b[id] = nb;
        o_t[id] = tau_new;

        float v0 = tau * W * invB;   // loss contribution
        float v1 = tau * invB;       // avg-tau contribution
#pragma unroll
        for (int o2 = 32; o2; o2 >>= 1) {
            v0 += __shfl_down(v0, o2);
            v1 += __shfl_down(v1, o2);
        }
        if (il == 0) {
            atomicAdd(&out[4 * BSZ + 0], v0);
            atomicAdd(&out[4 * BSZ + 1 + side], v1);
        }
    }
}

// ---------------------------------------------------------------------------
extern "C" void kernel_launch(void* const* d_in, const int* in_sizes, int n_in,
                              void* d_out, int out_size, void* d_ws, size_t ws_size,
                              hipStream_t stream) {
    const float* imf   = (const float*)d_in[0];
    const float* txf   = (const float*)d_in[1];
    const float* s_I   = (const float*)d_in[2];
    const float* s_T   = (const float*)d_in[3];
    const float* tau_I = (const float*)d_in[4];
    const float* tau_T = (const float*)d_in[5];
    const float* u_I   = (const float*)d_in[6];
    const float* u_T   = (const float*)d_in[7];
    const float* b_I   = (const float*)d_in[8];
    const float* b_T   = (const float*)d_in[9];
    const int* iid     = (const int*)d_in[10];
    const int* tid_    = (const int*)d_in[11];
    const int* epoch   = (const int*)d_in[12];
    const int* maxep   = (const int*)d_in[13];

    float* out = (float*)d_out;
    float* ws  = (float*)d_ws;

    float* diag  = ws + 0 * BSZ;
    float* tauIg = ws + 1 * BSZ;
    float* tauTg = ws + 2 * BSZ;
    float* obI   = ws + 3 * BSZ;
    float* obT   = ws + 4 * BSZ;
    float* rpM   = ws + 5 * BSZ;                   // 32 * BSZ each
    float* rpE   = rpM + (size_t)32 * BSZ;
    float* rpV   = rpE + (size_t)32 * BSZ;
    float* cpM   = rpV + (size_t)32 * BSZ;
    float* cpE   = cpM + (size_t)32 * BSZ;
    float* cpV   = cpE + (size_t)32 * BSZ;
    unsigned short* abf = (unsigned short*)(cpV + (size_t)32 * BSZ);
    unsigned short* bbf = abf + (size_t)BSZ * DIM;

    conv_diag<<<BSZ / 4, 256, 0, stream>>>(imf, txf, abf, bbf, tau_I, tau_T, b_I, b_T,
                                           iid, tid_, diag, tauIg, tauTg, obI, obT,
                                           out + 4 * BSZ);
    gemm_fused<<<2048, 256, 0, stream>>>(abf, bbf, diag, tauIg, tauTg,
                                         rpM, rpE, rpV, cpM, cpE, cpV,
                                         s_I, s_T, u_I, u_T, b_I, b_T, tau_I, tau_T,
                                         out + 4 * BSZ + 3);
    finalize<<<128, 256, 0, stream>>>(s_I, s_T, u_I, u_T, iid, tid_, epoch, maxep,
                                      tauIg, tauTg, obI, obT,
                                      rpM, rpE, rpV, cpM, cpE, cpV, out);
}